// Round 15
// baseline (183.913 us; speedup 1.0000x reference)
//
#include <hip/hip_runtime.h>
#include <math.h>

#define NN 12000
#define NP 12032            // padded rows (94*128)
#define CCD 512
#define KK 4096
#define TT 1500
#define S20F 28.853900817779268f   // 20*log2(e)
#define SC2F 14.426950408889634f   // 10*log2(e)
#define LN2F 0.6931471805599453f

typedef float f32x4 __attribute__((ext_vector_type(4)));
typedef __bf16 bf16x8 __attribute__((ext_vector_type(8)));

#if __has_builtin(__builtin_amdgcn_exp2f)
#define EXP2(x) __builtin_amdgcn_exp2f(x)
#else
static __device__ __forceinline__ float exp2_asm(float x){
  float r; asm("v_exp_f32 %0, %1" : "=v"(r) : "v"(x)); return r;
}
#define EXP2(x) exp2_asm(x)
#endif

__device__ __forceinline__ ushort f2bf(float f){
  uint u = __float_as_uint(f);
  uint r = (u + 0x7fffu + ((u >> 16) & 1u)) >> 16;
  return (ushort)r;
}

typedef __attribute__((address_space(1))) const unsigned int g_u32;
typedef __attribute__((address_space(3))) unsigned int l_u32;
__device__ __forceinline__ void gload_lds16(const void* g, void* l){
  __builtin_amdgcn_global_load_lds((g_u32*)g, (l_u32*)l, 16, 0, 0);
}

// ---- student (B,C,T) f32 -> zbf[N][C] bf16 (tiled transpose) ----
__global__ __launch_bounds__(256) void k_prep_z(const float* __restrict__ src, ushort* __restrict__ dst){
  __shared__ float tile[64][65];
  int b = blockIdx.z, c0 = blockIdx.y*64, t0 = blockIdx.x*64;
  const float* sb = src + ((size_t)b*CCD + c0)*TT + t0;
  for (int i = 0; i < 16; ++i){
    int e = i*256 + threadIdx.x;
    int cl = e >> 6, tl = e & 63;
    if (t0 + tl < TT) tile[cl][tl] = sb[(size_t)cl*TT + tl];
  }
  __syncthreads();
  for (int i = 0; i < 16; ++i){
    int e = i*256 + threadIdx.x;
    int tl = e >> 6, cl = e & 63;
    if (t0 + tl < TT) dst[((size_t)b*TT + t0 + tl)*CCD + c0 + cl] = f2bf(tile[cl][tl]);
  }
}

// ---- codebook f32 -> bf16 fragment-order image (LINEAR lds reads) ----
// cbsw uint4 slot id = tile*1024 + kstep*64 + l
//   tile 0..255 (16 codes each), kstep 0..15 (32 C each), l 0..63
//   holds codebook[code = tile*16 + (l&15)][c = kstep*32 + (l>>4)*8 ..+8]
// => k_dist reads are base + lane*16 + imm(kstep): zero bank conflicts.
__global__ __launch_bounds__(256) void k_prep_cb(const float* __restrict__ cb, ushort* __restrict__ cbsw){
  int id = blockIdx.x*256 + threadIdx.x;     // [0, 262144) uint4 slots
  int l     = id & 63;
  int kstep = (id >> 6) & 15;
  int tile  = id >> 10;
  int code  = tile*16 + (l & 15);
  int cc    = kstep*32 + (l >> 4)*8;
  const float* src = cb + ((size_t)code*CCD + cc);
  float4 v0 = *(const float4*)src;
  float4 v1 = *(const float4*)(src + 4);
  uint4 o;
  o.x = (uint)f2bf(v0.x) | ((uint)f2bf(v0.y) << 16);
  o.y = (uint)f2bf(v0.z) | ((uint)f2bf(v0.w) << 16);
  o.z = (uint)f2bf(v1.x) | ((uint)f2bf(v1.y) << 16);
  o.w = (uint)f2bf(v1.z) | ((uint)f2bf(v1.w) << 16);
  ((uint4*)cbsw)[id] = o;
}

// ---- per-code scaled squared norms: c2s[k] = ||c_k||^2 * 10*log2e ----
__global__ __launch_bounds__(256) void k_c2(const float* __restrict__ cb, float* __restrict__ c2s){
  int k = blockIdx.x*4 + (threadIdx.x >> 6);
  int lane = threadIdx.x & 63;
  const float4* p = (const float4*)(cb + (size_t)k*CCD);
  float s = 0.f;
  for (int i = lane; i < CCD/4; i += 64){
    float4 v = p[i];
    s += v.x*v.x + v.y*v.y + v.z*v.z + v.w*v.w;
  }
  for (int off=1; off<64; off<<=1) s += __shfl_xor(s, off);
  if (lane == 0) c2s[k] = s * SC2F;
}

// ---- fused bf16-MFMA distance GEMM ----
// R14 structure (92.5us champion) + T3/T4 counted-vmcnt pipeline:
// distance-2 prefetch over THREE 16KB LDS buffers; per-tile wait is
// s_waitcnt vmcnt(4) (only the NEXT tile's 4 loads must land; the tile
// after stays in flight) + raw s_barrier — never vmcnt(0) in the loop.
// R14 PMC: MFMA 20us + LDS 20us + VALU 31us on separate pipes but wall
// 92.5us => ~44% stall = stage latency exposed at every __syncthreads
// (compiler drains vmcnt(0) there). Buffer reuse safe: stage of
// buf[(t+2)%3] == buf[(t-1)%3], whose reads completed at barrier t-1.
// grid (8, 94): x = ksplit (512 codes), y = row block (128 rows)
// bid%8 == ksplit -> each XCD keeps its 512KB codebook slice L2-resident.
__global__ __launch_bounds__(256) void k_dist(const ushort* __restrict__ zbf,
    const ushort* __restrict__ cbsw, const float* __restrict__ c2s,
    const int* __restrict__ codes, float4* __restrict__ pstate){
  __shared__ char cs[3*16384];
  int tid = threadIdx.x, w = tid >> 6, l = tid & 63;
  int lm = l & 15, k16 = l >> 4;
  int yk = blockIdx.x, xb = blockIdx.y;
  int n0 = xb * 128, kb = yk * 512;

  // A fragments: 32 rows x 512 C per wave (128 regs/lane)
  bf16x8 A0[16], A1[16];
  {
    const ushort* a0 = zbf + (size_t)(n0 + w*32 + lm)*CCD + k16*8;
#pragma unroll
    for (int u = 0; u < 16; ++u){
      A0[u] = *(const bf16x8*)(a0 + u*32);
      A1[u] = *(const bf16x8*)(a0 + 16*CCD + u*32);
    }
  }
  // target codes for the 8 rows this lane owns (argmax exclusion)
  int tgt[8];
#pragma unroll
  for (int fi=0; fi<2; ++fi)
#pragma unroll
    for (int r=0; r<4; ++r){
      int n = n0 + w*32 + fi*16 + k16*4 + r;
      tgt[fi*4+r] = (n < NN) ? codes[n] : -1;
    }

  float m2[8], ss[8], bv[8]; int bi[8];
#pragma unroll
  for (int i=0;i<8;++i){ m2[i]=-3.0e38f; ss[i]=0.f; bv[i]=-3.0e38f; bi[i]=0x7fffffff; }

  // staging: 16KB tile, 4 x gload_lds16 per thread, both sides linear in tid
#define STAGE(tile, buf) { \
    const char* tb_ = (const char*)cbsw + ((size_t)(yk*32 + (tile)))*16384; \
    _Pragma("unroll") \
    for (int j_ = 0; j_ < 4; ++j_) \
      gload_lds16(tb_ + j_*4096 + tid*16, (buf) + j_*4096 + tid*16); }

  STAGE(0, cs)
  STAGE(1, cs + 16384)
  asm volatile("s_waitcnt vmcnt(4)" ::: "memory");   // stage(0) landed
  __builtin_amdgcn_s_barrier();

#pragma unroll
  for (int t = 0; t < 32; ++t){
    const char* cur = cs + (t % 3)*16384;
    if (t < 30) STAGE(t + 2, cs + ((t + 2) % 3)*16384)  // distance-2 prefetch

    f32x4 a0e = (f32x4){0.f,0.f,0.f,0.f}, a0o = a0e, a1e = a0e, a1o = a0e;
    const char* pb = cur + l*16;     // lane-linear base; rest is immediates
    __builtin_amdgcn_s_setprio(1);
#pragma unroll
    for (int ks = 0; ks < 16; ks += 2){
      bf16x8 b0 = *(const bf16x8*)(pb + ks*1024);
      bf16x8 b1 = *(const bf16x8*)(pb + ks*1024 + 1024);
      a0e = __builtin_amdgcn_mfma_f32_16x16x32_bf16(A0[ks],   b0, a0e, 0,0,0);
      a1e = __builtin_amdgcn_mfma_f32_16x16x32_bf16(A1[ks],   b0, a1e, 0,0,0);
      a0o = __builtin_amdgcn_mfma_f32_16x16x32_bf16(A0[ks+1], b1, a0o, 0,0,0);
      a1o = __builtin_amdgcn_mfma_f32_16x16x32_bf16(A1[ks+1], b1, a1o, 0,0,0);
    }
    __builtin_amdgcn_s_setprio(0);

    // epilogue: argmax (tgt-excluded) + online softmax over this tile's col
    int c0g = kb + t*16 + lm;
    float c2r0 = c2s[c0g];
    f32x4 accf[2];
    accf[0] = a0e + a0o;
    accf[1] = a1e + a1o;
#pragma unroll
    for (int fi=0; fi<2; ++fi)
#pragma unroll
    for (int r=0; r<4; ++r){
      int i8 = fi*4 + r;
      float v0 = fmaf(accf[fi][r], S20F, -c2r0);
      if (c0g != tgt[i8] && v0 > bv[i8]){ bv[i8] = v0; bi[i8] = c0g; }
      float mn = fmaxf(m2[i8], v0);
      ss[i8] = ss[i8]*EXP2(m2[i8]-mn) + EXP2(v0-mn);
      m2[i8] = mn;
    }

    if (t < 31){
      if (t < 30) asm volatile("s_waitcnt vmcnt(4)" ::: "memory"); // next tile landed
      else        asm volatile("s_waitcnt vmcnt(0)" ::: "memory"); // last stage
      __builtin_amdgcn_s_barrier();
      __builtin_amdgcn_sched_barrier(0);
    }
  }
#undef STAGE

  // butterfly over the 16 lanes sharing each row
#pragma unroll
  for (int off = 1; off < 16; off <<= 1){
#pragma unroll
    for (int i=0; i<8; ++i){
      float mo = __shfl_xor(m2[i], off);
      float so = __shfl_xor(ss[i], off);
      float bvo = __shfl_xor(bv[i], off);
      int  bio = __shfl_xor(bi[i], off);
      if (bvo > bv[i] || (bvo == bv[i] && bio < bi[i])){ bv[i] = bvo; bi[i] = bio; }
      float mn = fmaxf(m2[i], mo);
      ss[i] = ss[i]*EXP2(m2[i]-mn) + so*EXP2(mo-mn);
      m2[i] = mn;
    }
  }
  if (lm == 0){
#pragma unroll
    for (int fi=0; fi<2; ++fi)
#pragma unroll
    for (int r=0; r<4; ++r){
      int i8 = fi*4 + r;
      int row = w*32 + fi*16 + k16*4 + r;
      pstate[(size_t)yk*NP + n0 + row] =
          make_float4(m2[i8], ss[i8], bv[i8], __int_as_float(bi[i8]));
    }
  }
}

// ---- finalize: merge partials (prologue) + triplet + direction + feature
//      + exact fp32 logit[tgt] -> ce ----
__global__ __launch_bounds__(256) void k_final(const float* __restrict__ student,
    const float* __restrict__ teacher, const float* __restrict__ orig,
    const float* __restrict__ cb, const float4* __restrict__ pstate,
    const int* __restrict__ codes, const float* __restrict__ c2s,
    float* __restrict__ accs){
  __shared__ float red[6][4][64];
  __shared__ int   sh_hard[64];
  __shared__ float sh_lse[64];
  int tt = threadIdx.x & 63, cg = threadIdx.x >> 6;
  int n = blockIdx.x*64 + tt;
  bool ok = (n < NN);
  if (cg == 0){
    float m=-3.0e38f, s=0.f, bvv=-3.0e38f; int bii=0x7fffffff;
    if (ok){
      for (int sp = 0; sp < 8; ++sp){
        float4 p = pstate[(size_t)sp*NP + n];
        int pb = __float_as_int(p.w);
        if (p.z > bvv || (p.z == bvv && pb < bii)){ bvv = p.z; bii = pb; }
        float mn = fmaxf(m, p.x);
        s = s*EXP2(m - mn) + p.y*EXP2(p.x - mn);
        m = mn;
      }
    } else { bii = 0; s = 1.f; m = 0.f; }
    sh_hard[tt] = bii;
    sh_lse[tt]  = m + log2f(s);
  }
  __syncthreads();
  float dp2=0,dn2=0,mm=0,dd=0,md=0,dt=0;
  int tg = 0;
  if (ok){
    int hn = sh_hard[tt]; tg = codes[n];
    int b = n / TT, t = n - b*TT;
    size_t base = (size_t)b*CCD*TT + t;
    const float* ch = cb + (size_t)hn*CCD;
    const float* ct = cb + (size_t)tg*CCD;
    for (int c = cg*128; c < cg*128+128; ++c){
      float sv = student[base + (size_t)c*TT];
      float tv = teacher[base + (size_t)c*TT];
      float ov = orig[base + (size_t)c*TT];
      float cv = ch[c], wv = ct[c];
      float u = sv - tv; dp2 = fmaf(u,u,dp2);
      float v = tv - cv; dn2 = fmaf(v,v,dn2);
      float mv = sv - ov, dv = tv - ov;
      mm = fmaf(mv,mv,mm); dd = fmaf(dv,dv,dd); md = fmaf(mv,dv,md);
      dt = fmaf(sv, wv, dt);
    }
  }
  red[0][cg][tt]=dp2; red[1][cg][tt]=dn2; red[2][cg][tt]=mm;
  red[3][cg][tt]=dd;  red[4][cg][tt]=md;  red[5][cg][tt]=dt;
  __syncthreads();
  if (cg == 0){
    dp2 = red[0][0][tt]+red[0][1][tt]+red[0][2][tt]+red[0][3][tt];
    dn2 = red[1][0][tt]+red[1][1][tt]+red[1][2][tt]+red[1][3][tt];
    mm  = red[2][0][tt]+red[2][1][tt]+red[2][2][tt]+red[2][3][tt];
    dd  = red[3][0][tt]+red[3][1][tt]+red[3][2][tt]+red[3][3][tt];
    md  = red[4][0][tt]+red[4][1][tt]+red[4][2][tt]+red[4][3][tt];
    dt  = red[5][0][tt]+red[5][1][tt]+red[5][2][tt]+red[5][3][tt];
    float trip=0.f, dc=0.f, nv=0.f, ce=0.f;
    if (ok){
      float dpos = sqrtf(dp2), dneg = sqrtf(dn2);
      trip = fmaxf(dpos - dneg + 0.5f, 0.f);
      float mn = sqrtf(mm), dnn = sqrtf(dd);
      bool valid = (mn > 1e-6f) && (dnn > 1e-6f);
      float cosv = md / ((mn + 1e-8f)*(dnn + 1e-8f));
      if (valid){ dc = 1.f - cosv; nv = 1.f; }
      ce = sh_lse[tt] - (fmaf(dt, S20F, -c2s[tg]));
    }
    for (int off=1; off<64; off<<=1){
      trip += __shfl_xor(trip,off);
      dc   += __shfl_xor(dc,off);
      nv   += __shfl_xor(nv,off);
      dp2  += __shfl_xor(dp2,off);
      ce   += __shfl_xor(ce,off);
    }
    if (tt == 0){
      atomicAdd(&accs[0], trip); atomicAdd(&accs[1], dc);
      atomicAdd(&accs[2], nv);   atomicAdd(&accs[3], dp2);
      atomicAdd(&accs[4], ce);
    }
  }
}

__global__ void k_total(const float* __restrict__ accs, float* __restrict__ out){
  float feat = accs[3] / 6144000.f;         // 8*512*1500
  float trip = accs[0] / (float)NN;
  float ce   = (accs[4] / (float)NN) * LN2F;
  float nv   = accs[2] < 1.f ? 1.f : accs[2];
  float dc   = accs[1] / nv;
  out[0] = 2.f*feat + trip + ce + dc;
}

extern "C" void kernel_launch(void* const* d_in, const int* in_sizes, int n_in,
                              void* d_out, int out_size, void* d_ws, size_t ws_size,
                              hipStream_t stream){
  const float* student = (const float*)d_in[0];
  const float* teacher = (const float*)d_in[1];
  const float* cb      = (const float*)d_in[2];
  const int*   codes   = (const int*)d_in[3];
  const float* orig    = (const float*)d_in[4];

  char* ws = (char*)d_ws;
  ushort* zbf    = (ushort*)(ws);                  // 12032*512*2 = 12,320,768
  ushort* cbsw   = (ushort*)(ws + 12320768);       // 4,194,304
  float*  c2s    = (float*)(ws + 16515072);        // 16,384
  float4* pstate = (float4*)(ws + 16531456);       // 8*12032*16 = 1,540,096
  float*  accs   = (float*)(ws + 18071552);        // 8 floats
  hipMemsetAsync(ws + 18071552, 0, 64, stream);
  k_prep_cb<<<1024, 256, 0, stream>>>(cb, cbsw);
  k_c2<<<1024, 256, 0, stream>>>(cb, c2s);
  k_prep_z<<<dim3(24, 8, 8), 256, 0, stream>>>(student, zbf);
  k_dist<<<dim3(8, 94), 256, 0, stream>>>(zbf, cbsw, c2s, codes, pstate);
  k_final<<<188, 256, 0, stream>>>(student, teacher, orig, cb, pstate, codes, c2s, accs);
  k_total<<<1, 1, 0, stream>>>(accs, (float*)d_out);
}

// Round 16
// 147.208 us; speedup vs baseline: 1.2493x; 1.2493x over previous
//
#include <hip/hip_runtime.h>
#include <math.h>

#define NN 12000
#define NP 12032            // padded rows (94*128)
#define CCD 512
#define KK 4096
#define TT 1500
#define S20F 28.853900817779268f   // 20*log2(e)
#define SC2F 14.426950408889634f   // 10*log2(e)
#define LN2F 0.6931471805599453f

typedef float f32x4 __attribute__((ext_vector_type(4)));
typedef __bf16 bf16x8 __attribute__((ext_vector_type(8)));

#if __has_builtin(__builtin_amdgcn_exp2f)
#define EXP2(x) __builtin_amdgcn_exp2f(x)
#else
static __device__ __forceinline__ float exp2_asm(float x){
  float r; asm("v_exp_f32 %0, %1" : "=v"(r) : "v"(x)); return r;
}
#define EXP2(x) exp2_asm(x)
#endif

__device__ __forceinline__ ushort f2bf(float f){
  uint u = __float_as_uint(f);
  uint r = (u + 0x7fffu + ((u >> 16) & 1u)) >> 16;
  return (ushort)r;
}

typedef __attribute__((address_space(1))) const unsigned int g_u32;
typedef __attribute__((address_space(3))) unsigned int l_u32;
__device__ __forceinline__ void gload_lds16(const void* g, void* l){
  __builtin_amdgcn_global_load_lds((g_u32*)g, (l_u32*)l, 16, 0, 0);
}

// ---- student (B,C,T) f32 -> zbf[N][C] bf16 (tiled transpose) ----
__global__ __launch_bounds__(256) void k_prep_z(const float* __restrict__ src, ushort* __restrict__ dst){
  __shared__ float tile[64][65];
  int b = blockIdx.z, c0 = blockIdx.y*64, t0 = blockIdx.x*64;
  const float* sb = src + ((size_t)b*CCD + c0)*TT + t0;
  for (int i = 0; i < 16; ++i){
    int e = i*256 + threadIdx.x;
    int cl = e >> 6, tl = e & 63;
    if (t0 + tl < TT) tile[cl][tl] = sb[(size_t)cl*TT + tl];
  }
  __syncthreads();
  for (int i = 0; i < 16; ++i){
    int e = i*256 + threadIdx.x;
    int tl = e >> 6, cl = e & 63;
    if (t0 + tl < TT) dst[((size_t)b*TT + t0 + tl)*CCD + c0 + cl] = f2bf(tile[cl][tl]);
  }
}

// ---- codebook f32 -> bf16 fragment-order image + fused c2s norms ----
// cbsw uint4 slot id = tile*1024 + kstep*64 + l
//   tile 0..255 (16 codes each), kstep 0..15 (32 C each), l 0..63
//   holds codebook[code = tile*16 + (l&15)][c = kstep*32 + (l>>4)*8 ..+8]
// => k_dist reads are base + lane*16 + imm(kstep): zero bank conflicts.
// c2s fused: lanes l, l^16, l^32, l^48 share a code (32 C per wave) ->
// 2 shuffles + one atomicAdd per code per wave (16 partial adds per code).
__global__ __launch_bounds__(256) void k_prep_cb(const float* __restrict__ cb,
    ushort* __restrict__ cbsw, float* __restrict__ c2s){
  int id = blockIdx.x*256 + threadIdx.x;     // [0, 262144) uint4 slots
  int l     = id & 63;
  int kstep = (id >> 6) & 15;
  int tile  = id >> 10;
  int code  = tile*16 + (l & 15);
  int cc    = kstep*32 + (l >> 4)*8;
  const float* src = cb + ((size_t)code*CCD + cc);
  float4 v0 = *(const float4*)src;
  float4 v1 = *(const float4*)(src + 4);
  uint4 o;
  o.x = (uint)f2bf(v0.x) | ((uint)f2bf(v0.y) << 16);
  o.y = (uint)f2bf(v0.z) | ((uint)f2bf(v0.w) << 16);
  o.z = (uint)f2bf(v1.x) | ((uint)f2bf(v1.y) << 16);
  o.w = (uint)f2bf(v1.z) | ((uint)f2bf(v1.w) << 16);
  ((uint4*)cbsw)[id] = o;
  float s = v0.x*v0.x + v0.y*v0.y + v0.z*v0.z + v0.w*v0.w
          + v1.x*v1.x + v1.y*v1.y + v1.z*v1.z + v1.w*v1.w;
  s += __shfl_xor(s, 16);
  s += __shfl_xor(s, 32);
  if ((l >> 4) == 0) atomicAdd(&c2s[code], s * SC2F);
}

// ---- fused bf16-MFMA distance GEMM ----
// R14 structure verbatim (92.5us champion: 4 indep MFMA chains, 16-code/16KB
// ping-pong tiles, lane-linear conflict-free LDS reads, no spill, 1-inst
// exp2). ONLY epilogue change: |d| single-exp2 online softmax
// (e=exp2(-|v0-m|); ss = d>0 ? fma(ss,e,1) : ss+e) — halves trans-pipe ops,
// zero new live state. (R13/R15 lesson: any scheduling scaffolding that
// extends live ranges on this kernel spills/deoccupies and loses.)
// grid (8, 94): x = ksplit (512 codes), y = row block (128 rows)
// bid%8 == ksplit -> each XCD keeps its 512KB codebook slice L2-resident.
__global__ __launch_bounds__(256) void k_dist(const ushort* __restrict__ zbf,
    const ushort* __restrict__ cbsw, const float* __restrict__ c2s,
    const int* __restrict__ codes, float4* __restrict__ pstate){
  __shared__ char cs[2*16384];
  int tid = threadIdx.x, w = tid >> 6, l = tid & 63;
  int lm = l & 15, k16 = l >> 4;
  int yk = blockIdx.x, xb = blockIdx.y;
  int n0 = xb * 128, kb = yk * 512;

  // A fragments: 32 rows x 512 C per wave (128 regs/lane)
  bf16x8 A0[16], A1[16];
  {
    const ushort* a0 = zbf + (size_t)(n0 + w*32 + lm)*CCD + k16*8;
#pragma unroll
    for (int u = 0; u < 16; ++u){
      A0[u] = *(const bf16x8*)(a0 + u*32);
      A1[u] = *(const bf16x8*)(a0 + 16*CCD + u*32);
    }
  }
  // target codes for the 8 rows this lane owns (argmax exclusion)
  int tgt[8];
#pragma unroll
  for (int fi=0; fi<2; ++fi)
#pragma unroll
    for (int r=0; r<4; ++r){
      int n = n0 + w*32 + fi*16 + k16*4 + r;
      tgt[fi*4+r] = (n < NN) ? codes[n] : -1;
    }

  float m2[8], ss[8], bv[8]; int bi[8];
#pragma unroll
  for (int i=0;i<8;++i){ m2[i]=-3.0e38f; ss[i]=0.f; bv[i]=-3.0e38f; bi[i]=0x7fffffff; }

  // staging: 16KB tile, 4 x gload_lds16 per thread, both sides linear in tid
#define STAGE(tile, buf) { \
    const char* tb_ = (const char*)cbsw + ((size_t)(yk*32 + (tile)))*16384; \
    _Pragma("unroll") \
    for (int j_ = 0; j_ < 4; ++j_) \
      gload_lds16(tb_ + j_*4096 + tid*16, (buf) + j_*4096 + tid*16); }

  STAGE(0, cs)
  __syncthreads();

#pragma unroll 2
  for (int t = 0; t < 32; ++t){
    const char* cur = cs + (t & 1)*16384;
    char* nxt = cs + ((t + 1) & 1)*16384;
    if (t < 31) STAGE(t + 1, nxt)    // issue next tile's loads before compute

    f32x4 a0e = (f32x4){0.f,0.f,0.f,0.f}, a0o = a0e, a1e = a0e, a1o = a0e;
    const char* pb = cur + l*16;     // lane-linear base; rest is immediates
    __builtin_amdgcn_s_setprio(1);
#pragma unroll
    for (int ks = 0; ks < 16; ks += 2){
      bf16x8 b0 = *(const bf16x8*)(pb + ks*1024);
      bf16x8 b1 = *(const bf16x8*)(pb + ks*1024 + 1024);
      a0e = __builtin_amdgcn_mfma_f32_16x16x32_bf16(A0[ks],   b0, a0e, 0,0,0);
      a1e = __builtin_amdgcn_mfma_f32_16x16x32_bf16(A1[ks],   b0, a1e, 0,0,0);
      a0o = __builtin_amdgcn_mfma_f32_16x16x32_bf16(A0[ks+1], b1, a0o, 0,0,0);
      a1o = __builtin_amdgcn_mfma_f32_16x16x32_bf16(A1[ks+1], b1, a1o, 0,0,0);
    }
    __builtin_amdgcn_s_setprio(0);

    // epilogue: argmax (tgt-excluded) + |d| single-exp2 online softmax
    int c0g = kb + t*16 + lm;
    float c2r0 = c2s[c0g];
    f32x4 accf[2];
    accf[0] = a0e + a0o;
    accf[1] = a1e + a1o;
#pragma unroll
    for (int fi=0; fi<2; ++fi)
#pragma unroll
    for (int r=0; r<4; ++r){
      int i8 = fi*4 + r;
      float v0 = fmaf(accf[fi][r], S20F, -c2r0);
      if (c0g != tgt[i8] && v0 > bv[i8]){ bv[i8] = v0; bi[i8] = c0g; }
      float d = v0 - m2[i8];
      float e = EXP2(-fabsf(d));
      ss[i8] = (d > 0.f) ? fmaf(ss[i8], e, 1.f) : (ss[i8] + e);
      m2[i8] = fmaxf(m2[i8], v0);
    }
    __syncthreads();   // next tile staged; all reads of cur done
  }
#undef STAGE

  // butterfly over the 16 lanes sharing each row
#pragma unroll
  for (int off = 1; off < 16; off <<= 1){
#pragma unroll
    for (int i=0; i<8; ++i){
      float mo = __shfl_xor(m2[i], off);
      float so = __shfl_xor(ss[i], off);
      float bvo = __shfl_xor(bv[i], off);
      int  bio = __shfl_xor(bi[i], off);
      if (bvo > bv[i] || (bvo == bv[i] && bio < bi[i])){ bv[i] = bvo; bi[i] = bio; }
      float mn = fmaxf(m2[i], mo);
      ss[i] = ss[i]*EXP2(m2[i]-mn) + so*EXP2(mo-mn);
      m2[i] = mn;
    }
  }
  if (lm == 0){
#pragma unroll
    for (int fi=0; fi<2; ++fi)
#pragma unroll
    for (int r=0; r<4; ++r){
      int i8 = fi*4 + r;
      int row = w*32 + fi*16 + k16*4 + r;
      pstate[(size_t)yk*NP + n0 + row] =
          make_float4(m2[i8], ss[i8], bv[i8], __int_as_float(bi[i8]));
    }
  }
}

// ---- finalize: merge partials (prologue) + triplet + direction + feature
//      + exact fp32 logit[tgt] -> ce ----
__global__ __launch_bounds__(256) void k_final(const float* __restrict__ student,
    const float* __restrict__ teacher, const float* __restrict__ orig,
    const float* __restrict__ cb, const float4* __restrict__ pstate,
    const int* __restrict__ codes, const float* __restrict__ c2s,
    float* __restrict__ accs){
  __shared__ float red[6][4][64];
  __shared__ int   sh_hard[64];
  __shared__ float sh_lse[64];
  int tt = threadIdx.x & 63, cg = threadIdx.x >> 6;
  int n = blockIdx.x*64 + tt;
  bool ok = (n < NN);
  if (cg == 0){
    float m=-3.0e38f, s=0.f, bvv=-3.0e38f; int bii=0x7fffffff;
    if (ok){
      for (int sp = 0; sp < 8; ++sp){
        float4 p = pstate[(size_t)sp*NP + n];
        int pb = __float_as_int(p.w);
        if (p.z > bvv || (p.z == bvv && pb < bii)){ bvv = p.z; bii = pb; }
        float mn = fmaxf(m, p.x);
        s = s*EXP2(m - mn) + p.y*EXP2(p.x - mn);
        m = mn;
      }
    } else { bii = 0; s = 1.f; m = 0.f; }
    sh_hard[tt] = bii;
    sh_lse[tt]  = m + log2f(s);
  }
  __syncthreads();
  float dp2=0,dn2=0,mm=0,dd=0,md=0,dt=0;
  int tg = 0;
  if (ok){
    int hn = sh_hard[tt]; tg = codes[n];
    int b = n / TT, t = n - b*TT;
    size_t base = (size_t)b*CCD*TT + t;
    const float* ch = cb + (size_t)hn*CCD;
    const float* ct = cb + (size_t)tg*CCD;
    for (int c = cg*128; c < cg*128+128; ++c){
      float sv = student[base + (size_t)c*TT];
      float tv = teacher[base + (size_t)c*TT];
      float ov = orig[base + (size_t)c*TT];
      float cv = ch[c], wv = ct[c];
      float u = sv - tv; dp2 = fmaf(u,u,dp2);
      float v = tv - cv; dn2 = fmaf(v,v,dn2);
      float mv = sv - ov, dv = tv - ov;
      mm = fmaf(mv,mv,mm); dd = fmaf(dv,dv,dd); md = fmaf(mv,dv,md);
      dt = fmaf(sv, wv, dt);
    }
  }
  red[0][cg][tt]=dp2; red[1][cg][tt]=dn2; red[2][cg][tt]=mm;
  red[3][cg][tt]=dd;  red[4][cg][tt]=md;  red[5][cg][tt]=dt;
  __syncthreads();
  if (cg == 0){
    dp2 = red[0][0][tt]+red[0][1][tt]+red[0][2][tt]+red[0][3][tt];
    dn2 = red[1][0][tt]+red[1][1][tt]+red[1][2][tt]+red[1][3][tt];
    mm  = red[2][0][tt]+red[2][1][tt]+red[2][2][tt]+red[2][3][tt];
    dd  = red[3][0][tt]+red[3][1][tt]+red[3][2][tt]+red[3][3][tt];
    md  = red[4][0][tt]+red[4][1][tt]+red[4][2][tt]+red[4][3][tt];
    dt  = red[5][0][tt]+red[5][1][tt]+red[5][2][tt]+red[5][3][tt];
    float trip=0.f, dc=0.f, nv=0.f, ce=0.f;
    if (ok){
      float dpos = sqrtf(dp2), dneg = sqrtf(dn2);
      trip = fmaxf(dpos - dneg + 0.5f, 0.f);
      float mn = sqrtf(mm), dnn = sqrtf(dd);
      bool valid = (mn > 1e-6f) && (dnn > 1e-6f);
      float cosv = md / ((mn + 1e-8f)*(dnn + 1e-8f));
      if (valid){ dc = 1.f - cosv; nv = 1.f; }
      ce = sh_lse[tt] - (fmaf(dt, S20F, -c2s[tg]));
    }
    for (int off=1; off<64; off<<=1){
      trip += __shfl_xor(trip,off);
      dc   += __shfl_xor(dc,off);
      nv   += __shfl_xor(nv,off);
      dp2  += __shfl_xor(dp2,off);
      ce   += __shfl_xor(ce,off);
    }
    if (tt == 0){
      atomicAdd(&accs[0], trip); atomicAdd(&accs[1], dc);
      atomicAdd(&accs[2], nv);   atomicAdd(&accs[3], dp2);
      atomicAdd(&accs[4], ce);
    }
  }
}

__global__ void k_total(const float* __restrict__ accs, float* __restrict__ out){
  float feat = accs[3] / 6144000.f;         // 8*512*1500
  float trip = accs[0] / (float)NN;
  float ce   = (accs[4] / (float)NN) * LN2F;
  float nv   = accs[2] < 1.f ? 1.f : accs[2];
  float dc   = accs[1] / nv;
  out[0] = 2.f*feat + trip + ce + dc;
}

extern "C" void kernel_launch(void* const* d_in, const int* in_sizes, int n_in,
                              void* d_out, int out_size, void* d_ws, size_t ws_size,
                              hipStream_t stream){
  const float* student = (const float*)d_in[0];
  const float* teacher = (const float*)d_in[1];
  const float* cb      = (const float*)d_in[2];
  const int*   codes   = (const int*)d_in[3];
  const float* orig    = (const float*)d_in[4];

  char* ws = (char*)d_ws;
  ushort* zbf    = (ushort*)(ws);                  // 12032*512*2 = 12,320,768
  ushort* cbsw   = (ushort*)(ws + 12320768);       // 4,194,304 -> ends 16,515,072
  float4* pstate = (float4*)(ws + 16515072);       // 8*12032*16 = 1,540,096 -> 18,055,168
  float*  c2s    = (float*)(ws + 18055168);        // 16,384 -> 18,071,552
  float*  accs   = (float*)(ws + 18071552);        // 64
  hipMemsetAsync(ws + 18055168, 0, 16448, stream); // c2s + accs in one shot
  k_prep_cb<<<1024, 256, 0, stream>>>(cb, cbsw, c2s);
  k_prep_z<<<dim3(24, 8, 8), 256, 0, stream>>>(student, zbf);
  k_dist<<<dim3(8, 94), 256, 0, stream>>>(zbf, cbsw, c2s, codes, pstate);
  k_final<<<188, 256, 0, stream>>>(student, teacher, orig, cb, pstate, codes, c2s, accs);
  k_total<<<1, 1, 0, stream>>>(accs, (float*)d_out);
}